// Round 7
// baseline (1024.305 us; speedup 1.0000x reference)
//
#include <hip/hip_runtime.h>
#include <hip/hip_bf16.h>
#include <hip/hip_cooperative_groups.h>
#include <cstdint>

namespace cg = cooperative_groups;

#define N_NODES 100000
#define N_EDGES 1600000
#define F_IN 256
#define F_HID 128
#define F_OUT 64
#define NEG_SLOPE 0.2f

// bucketed CSR build
#define BSH 7                      // 128 nodes per bucket
#define NB 782                     // ceil(100000/128)
#define CAP 3072                   // csr slots per bucket (edges+selfloops)
#define CAPS 3072                  // staged slots per bucket (edges only)
#define NBLK_E 256                 // edge-chunk units (== escan scan width)
#define NT1 1563                   // gemm tiles (BM=64)
#define NAGG 25000                 // node groups of 4 (1 per wave)

typedef __attribute__((ext_vector_type(8))) short bf16x8;
typedef __attribute__((ext_vector_type(4))) float f32x4;

// ---------------- ws layout (constexpr, device+host agree) ----------------
constexpr size_t AL(size_t x) { return (x + 255) & ~(size_t)255; }
constexpr size_t OFF_H1B = 0;
constexpr size_t OFF_HRB = OFF_H1B + AL((size_t)N_NODES * F_HID * 2);
constexpr size_t OFF_H2B = OFF_HRB + AL((size_t)N_NODES * F_HID * 2);
constexpr size_t OFF_AS1 = OFF_H2B + AL((size_t)N_NODES * F_OUT * 2);
constexpr size_t OFF_AD1 = OFF_AS1 + AL((size_t)N_NODES * 4);
constexpr size_t OFF_AS2 = OFF_AD1 + AL((size_t)N_NODES * 4);
constexpr size_t OFF_AD2 = OFF_AS2 + AL((size_t)N_NODES * 4);
constexpr size_t OFF_CNT = OFF_AD2 + AL((size_t)N_NODES * 4);
constexpr size_t OFF_OFF = OFF_CNT + AL((size_t)N_NODES * 4);
constexpr size_t OFF_HB  = OFF_OFF + AL((size_t)N_NODES * 4);
constexpr size_t OFF_BT  = OFF_HB + AL((size_t)NBLK_E * NB * 4);
constexpr size_t OFF_STG = OFF_BT + AL((size_t)NB * 4);
constexpr size_t OFF_CSR = OFF_STG + AL((size_t)NB * CAPS * 4);
constexpr size_t OFF_W1T = OFF_CSR + AL((size_t)NB * CAP * 4);
constexpr size_t OFF_W2T = OFF_W1T + AL((size_t)F_IN * F_HID * 2);

__device__ __forceinline__ ushort f2bf(float f) {
  uint u = __float_as_uint(f);
  u += 0x7fffu + ((u >> 16) & 1u);   // RNE
  return (ushort)(u >> 16);
}
__device__ __forceinline__ float bf2f(ushort s) {
  return __uint_as_float(((uint)s) << 16);
}
__device__ __forceinline__ uint pack2(float a, float b) {
  return (uint)f2bf(a) | ((uint)f2bf(b) << 16);
}

// ----------------------------------------------------------- GEMM tile ----
// BM=64 (4 waves x 16 rows), BN full width, K-step 32, 16x16x32 mfma,
// fused bf16 C-write + alpha dot epilogue. acc = 32 VGPR (fits 128 cap).
template <int BN, int K, bool AF32>
__device__ void gemm_tile(int tile, const void* __restrict__ Ap,
                          const ushort* __restrict__ Bt, ushort* __restrict__ Cb,
                          const float* __restrict__ a_src, const float* __restrict__ a_dst,
                          float* __restrict__ as_, float* __restrict__ ad_,
                          char* smem, int tid) {
  constexpr int CT = BN / 16;
  ushort* Alds = (ushort*)smem;                // 64*32 bf16 = 4KB
  ushort* Blds = ((ushort*)smem) + 64 * 32;    // BN*32 bf16
  const int wave = tid >> 6, lane = tid & 63;
  const int lr = lane & 15, lq = lane >> 4;
  const int gm0 = tile * 64;

  f32x4 acc[CT];
#pragma unroll
  for (int c = 0; c < CT; ++c)
#pragma unroll
    for (int e = 0; e < 4; ++e) acc[c][e] = 0.f;

  __syncthreads();  // unit boundary (smem may be in use by previous unit)
  for (int kt = 0; kt < K; kt += 32) {
    {  // A stage: 256 segs of 8 bf16, seg-XOR swizzled
      int row = tid >> 2, q = tid & 3;
      int gm = gm0 + row;
      uint4 w = make_uint4(0u, 0u, 0u, 0u);
      if (gm < N_NODES) {
        if (AF32) {
          const float* s = (const float*)Ap + (size_t)gm * K + kt + q * 8;
          float4 u = *(const float4*)s;
          float4 v = *(const float4*)(s + 4);
          w.x = pack2(u.x, u.y); w.y = pack2(u.z, u.w);
          w.z = pack2(v.x, v.y); w.w = pack2(v.z, v.w);
        } else {
          w = *(const uint4*)((const ushort*)Ap + (size_t)gm * K + kt + q * 8);
        }
      }
      int phys = row * 4 + (q ^ ((row >> 2) & 3));
      *(uint4*)&Alds[phys * 8] = w;
    }
#pragma unroll
    for (int i = 0; i < BN * 4 / 256; ++i) {
      int sid = i * 256 + tid;
      int row = sid >> 2, q = sid & 3;
      uint4 w = *(const uint4*)(Bt + (size_t)row * K + kt + q * 8);
      int phys = row * 4 + (q ^ ((row >> 2) & 3));
      *(uint4*)&Blds[phys * 8] = w;
    }
    __syncthreads();

    bf16x8 af, bfr[CT];
    {
      int r = wave * 16 + lr;
      af = *(const bf16x8*)&Alds[(r * 4 + (lq ^ ((r >> 2) & 3))) * 8];
    }
#pragma unroll
    for (int c = 0; c < CT; ++c) {
      int r = c * 16 + lr;
      bfr[c] = *(const bf16x8*)&Blds[(r * 4 + (lq ^ ((r >> 2) & 3))) * 8];
    }
#pragma unroll
    for (int c = 0; c < CT; ++c)
      acc[c] = __builtin_amdgcn_mfma_f32_16x16x32_bf16(af, bfr[c], acc[c], 0, 0, 0);
    __syncthreads();
  }

  // C/D layout: col=lane&15, row=(lane>>4)*4+reg
#pragma unroll
  for (int ri = 0; ri < 4; ++ri) {
    int gr = gm0 + wave * 16 + lq * 4 + ri;
    if (gr < N_NODES) {
#pragma unroll
      for (int c = 0; c < CT; ++c)
        Cb[(size_t)gr * BN + c * 16 + lr] = f2bf(acc[c][ri]);
    }
  }

  // fused alpha dots
  float avs[CT], avd[CT];
#pragma unroll
  for (int c = 0; c < CT; ++c) {
    avs[c] = a_src[c * 16 + lr];
    avd[c] = a_dst[c * 16 + lr];
  }
#pragma unroll
  for (int ri = 0; ri < 4; ++ri) {
    int gr = gm0 + wave * 16 + lq * 4 + ri;
    float s = 0.f, d = 0.f;
#pragma unroll
    for (int c = 0; c < CT; ++c) {
      s += acc[c][ri] * avs[c];
      d += acc[c][ri] * avd[c];
    }
#pragma unroll
    for (int off = 1; off < 16; off <<= 1) {
      s += __shfl_xor(s, off);
      d += __shfl_xor(d, off);
    }
    if (gr < N_NODES && lr == 0) {
      as_[gr] = s;
      ad_[gr] = d;
    }
  }
}

// ------------------------------------------------------- CSR build units ----
__device__ void ehist_unit(int c, const int* __restrict__ edst,
                           int* __restrict__ hist_blk, char* smem, int t) {
  int* h = (int*)smem;
  __syncthreads();
  for (int i = t; i < NB; i += 256) h[i] = 0;
  __syncthreads();
  const int per = (N_EDGES + NBLK_E - 1) / NBLK_E;
  const int e0 = c * per, e1 = min(e0 + per, N_EDGES);
  for (int i = e0 + t; i < e1; i += 256) atomicAdd(&h[edst[i] >> BSH], 1);
  __syncthreads();
  for (int i = t; i < NB; i += 256) hist_blk[c * NB + i] = h[i];
}

__device__ void escan_unit(int j, int* __restrict__ hist_blk,
                           int* __restrict__ btotal, char* smem, int t) {
  int* sh = (int*)smem;
  __syncthreads();
  int v = hist_blk[t * NB + j];
  sh[t] = v;
  __syncthreads();
  for (int off = 1; off < NBLK_E; off <<= 1) {
    int x = (t >= off) ? sh[t - off] : 0;
    __syncthreads();
    sh[t] += x;
    __syncthreads();
  }
  hist_blk[t * NB + j] = sh[t] - v;  // exclusive base for (chunk t, bucket j)
  if (t == NBLK_E - 1) btotal[j] = sh[NBLK_E - 1];
}

__device__ void escatter_unit(int c, const int* __restrict__ src,
                              const int* __restrict__ dst,
                              const int* __restrict__ hist_blk,
                              uint* __restrict__ staged, char* smem, int t) {
  int* cur = (int*)smem;
  __syncthreads();
  for (int i = t; i < NB; i += 256) cur[i] = hist_blk[c * NB + i];
  __syncthreads();
  const int per = (N_EDGES + NBLK_E - 1) / NBLK_E;
  const int e0 = c * per, e1 = min(e0 + per, N_EDGES);
  for (int i = e0 + t; i < e1; i += 256) {
    int d = dst[i];
    int b = d >> BSH;
    int p = atomicAdd(&cur[b], 1);
    if (p < CAPS)
      staged[(size_t)b * CAPS + p] = ((uint)src[i] << BSH) | (uint)(d & ((1 << BSH) - 1));
  }
}

__device__ void fine_unit(int b, const uint* __restrict__ staged,
                          const int* __restrict__ btotal, int* __restrict__ counts,
                          int* __restrict__ offs, int* __restrict__ csr_src,
                          char* smem, int t) {
  int* hist = (int*)smem;
  int* cur = hist + 128;
  const int n0 = b << BSH;
  const int nn = min(128, N_NODES - n0);
  __syncthreads();
  if (t < 128) hist[t] = 0;
  __syncthreads();
  const int ce = min(btotal[b], CAPS);
  const uint* sp = staged + (size_t)b * CAPS;
  for (int i = t; i < ce; i += 256) atomicAdd(&hist[sp[i] & 127], 1);
  __syncthreads();
  int v = 0;
  if (t < 128) {
    v = (t < nn) ? hist[t] + 1 : 0;
    cur[t] = v;
  }
  __syncthreads();
  for (int off = 1; off < 128; off <<= 1) {
    int x = 0;
    if (t < 128 && t >= off) x = cur[t - off];
    __syncthreads();
    if (t < 128) cur[t] += x;
    __syncthreads();
  }
  int excl = (t < 128) ? cur[t] - v : 0;
  __syncthreads();
  if (t < nn) {
    counts[n0 + t] = v;
    offs[n0 + t] = b * CAP + excl;
    csr_src[b * CAP + excl] = n0 + t;     // self loop first
    cur[t] = excl + 1;
  }
  __syncthreads();
  for (int i = t; i < ce; i += 256) {
    uint e = sp[i];
    int p = atomicAdd(&cur[e & 127], 1);
    csr_src[b * CAP + p] = (int)(e >> BSH);
  }
}

// ------------------------------------------------------- GAT aggregation ----
template <int C, bool RELU, bool OUTBF>
__device__ void agg_node(int wid, int lane, const ushort* __restrict__ h,
                         const float* __restrict__ as_, const float* __restrict__ ad_,
                         const int* __restrict__ offs, const int* __restrict__ counts,
                         const int* __restrict__ csr_src, const float* __restrict__ bias,
                         void* __restrict__ outp) {
  if (wid >= N_NODES) return;
  const int start = offs[wid];
  const int cnt = counts[wid];
  const float adn = ad_[wid];

  // pass 1: online max + denom; keep first-chunk (sj,e) in registers
  float m = -3.402823e38f, ssum = 0.f;
  int sj0 = 0;
  float e0 = -3.402823e38f;
  for (int j = lane; j < cnt; j += 64) {
    int sj = csr_src[start + j];
    float e = as_[sj] + adn;
    e = (e >= 0.f) ? e : NEG_SLOPE * e;
    if (j < 64) { sj0 = sj; e0 = e; }
    float mn = fmaxf(m, e);
    ssum = ssum * __expf(m - mn) + __expf(e - mn);
    m = mn;
  }
#pragma unroll
  for (int off = 32; off; off >>= 1) {
    float mo = __shfl_xor(m, off), so = __shfl_xor(ssum, off);
    float mn = fmaxf(m, mo);
    ssum = ssum * __expf(m - mn) + so * __expf(mo - mn);
    m = mn;
  }
  const float inv = 1.0f / ssum;

  float2 acc = make_float2(0.f, 0.f);
  const int half = lane >> 5;
  const int cl = lane & 31;

  for (int j0 = 0; j0 < cnt; j0 += 64) {
    int j = j0 + lane;
    int sj;
    float pj;
    if (j0 == 0) {
      sj = sj0;
      pj = __expf(e0 - m) * inv;   // e0=-3.4e38 for idle lanes -> pj=0
    } else {
      sj = 0;
      pj = 0.f;
      if (j < cnt) {
        sj = csr_src[start + j];
        float e = as_[sj] + adn;
        e = (e >= 0.f) ? e : NEG_SLOPE * e;
        pj = __expf(e - m) * inv;
      }
    }
    int c2 = min(64, cnt - j0);
    int jj = 0;
    if (C == 128) {
      for (; jj + 16 <= c2; jj += 16) {
        uint vv[16];
        float pp[16];
#pragma unroll
        for (int q = 0; q < 16; ++q) {
          int sq = __builtin_amdgcn_readlane(sj, jj + q);
          pp[q] = __uint_as_float((uint)__builtin_amdgcn_readlane((int)__float_as_uint(pj), jj + q));
          vv[q] = *((const uint*)(h + (size_t)sq * C) + lane);
        }
#pragma unroll
        for (int q = 0; q < 16; ++q) {
          acc.x = fmaf(pp[q], bf2f((ushort)(vv[q] & 0xffffu)), acc.x);
          acc.y = fmaf(pp[q], bf2f((ushort)(vv[q] >> 16)), acc.y);
        }
      }
      for (; jj + 4 <= c2; jj += 4) {
        uint vv[4];
        float pp[4];
#pragma unroll
        for (int q = 0; q < 4; ++q) {
          int sq = __builtin_amdgcn_readlane(sj, jj + q);
          pp[q] = __uint_as_float((uint)__builtin_amdgcn_readlane((int)__float_as_uint(pj), jj + q));
          vv[q] = *((const uint*)(h + (size_t)sq * C) + lane);
        }
#pragma unroll
        for (int q = 0; q < 4; ++q) {
          acc.x = fmaf(pp[q], bf2f((ushort)(vv[q] & 0xffffu)), acc.x);
          acc.y = fmaf(pp[q], bf2f((ushort)(vv[q] >> 16)), acc.y);
        }
      }
      for (; jj < c2; ++jj) {
        int sq = __builtin_amdgcn_readlane(sj, jj);
        float pq = __uint_as_float((uint)__builtin_amdgcn_readlane((int)__float_as_uint(pj), jj));
        uint v = *((const uint*)(h + (size_t)sq * C) + lane);
        acc.x = fmaf(pq, bf2f((ushort)(v & 0xffffu)), acc.x);
        acc.y = fmaf(pq, bf2f((ushort)(v >> 16)), acc.y);
      }
    } else {
      const uint* h32 = (const uint*)h;
      for (; jj + 16 <= c2; jj += 16) {
        uint vv[8];
        float pp[8];
#pragma unroll
        for (int q = 0; q < 8; ++q) {
          int idx = jj + 2 * q + half;
          int sq = __shfl(sj, idx);
          pp[q] = __shfl(pj, idx);
          vv[q] = h32[(size_t)sq * (C / 2) + cl];
        }
#pragma unroll
        for (int q = 0; q < 8; ++q) {
          acc.x = fmaf(pp[q], bf2f((ushort)(vv[q] & 0xffffu)), acc.x);
          acc.y = fmaf(pp[q], bf2f((ushort)(vv[q] >> 16)), acc.y);
        }
      }
      for (; jj < c2; jj += 2) {
        int idx = jj + half;
        int idc = min(idx, c2 - 1);
        int sq = __shfl(sj, idc);
        float pq = __shfl(pj, idc);
        if (idx >= c2) pq = 0.f;
        uint v = h32[(size_t)sq * (C / 2) + cl];
        acc.x = fmaf(pq, bf2f((ushort)(v & 0xffffu)), acc.x);
        acc.y = fmaf(pq, bf2f((ushort)(v >> 16)), acc.y);
      }
    }
  }

  if (C == 128) {
    float r0 = acc.x + bias[2 * lane];
    float r1 = acc.y + bias[2 * lane + 1];
    if (RELU) {
      r0 = fmaxf(r0, 0.f);
      r1 = fmaxf(r1, 0.f);
    }
    if (OUTBF)
      ((uint*)outp)[(size_t)wid * (C / 2) + lane] = pack2(r0, r1);
    else
      ((float2*)outp)[(size_t)wid * (C / 2) + lane] = make_float2(r0, r1);
  } else {
    acc.x += __shfl_xor(acc.x, 32);
    acc.y += __shfl_xor(acc.y, 32);
    if (lane < 32) {
      float r0 = acc.x + bias[2 * cl];
      float r1 = acc.y + bias[2 * cl + 1];
      if (RELU) {
        r0 = fmaxf(r0, 0.f);
        r1 = fmaxf(r1, 0.f);
      }
      if (OUTBF)
        ((uint*)outp)[(size_t)wid * (C / 2) + cl] = pack2(r0, r1);
      else
        ((float2*)outp)[(size_t)wid * (C / 2) + cl] = make_float2(r0, r1);
    }
  }
}

// ---------------------------------------------------------- mega kernel ----
__global__ __launch_bounds__(256, 4) void mega_kernel(
    const float* __restrict__ x, const int* __restrict__ ei,
    const float* __restrict__ W1, const float* __restrict__ a1s,
    const float* __restrict__ a1d, const float* __restrict__ b1,
    const float* __restrict__ W2, const float* __restrict__ a2s,
    const float* __restrict__ a2d, const float* __restrict__ b2,
    float* __restrict__ out, char* __restrict__ ws) {
  __shared__ __align__(16) char smem[12288];   // max(gemm1 12KB, NB ints 3.1KB)
  cg::grid_group grid = cg::this_grid();
  const int tid = threadIdx.x;
  const int bid = blockIdx.x;
  const int nblk = gridDim.x;
  const int wave = tid >> 6, lane = tid & 63;

  const int* esrc = ei;
  const int* edst = ei + N_EDGES;
  ushort* h1b = (ushort*)(ws + OFF_H1B);
  ushort* hrb = (ushort*)(ws + OFF_HRB);
  ushort* h2b = (ushort*)(ws + OFF_H2B);
  float* as1 = (float*)(ws + OFF_AS1);
  float* ad1 = (float*)(ws + OFF_AD1);
  float* as2 = (float*)(ws + OFF_AS2);
  float* ad2 = (float*)(ws + OFF_AD2);
  int* counts = (int*)(ws + OFF_CNT);
  int* offs = (int*)(ws + OFF_OFF);
  int* hist_blk = (int*)(ws + OFF_HB);
  int* btotal = (int*)(ws + OFF_BT);
  uint* staged = (uint*)(ws + OFF_STG);
  int* csr = (int*)(ws + OFF_CSR);
  ushort* W1t = (ushort*)(ws + OFF_W1T);
  ushort* W2t = (ushort*)(ws + OFF_W2T);

  // P0: weight transpose + bf16
  for (int i = bid * 256 + tid; i < F_IN * F_HID; i += nblk * 256) {
    int k = i / F_HID, c = i % F_HID;
    W1t[c * F_IN + k] = f2bf(W1[i]);
  }
  for (int i = bid * 256 + tid; i < F_HID * F_OUT; i += nblk * 256) {
    int k = i / F_OUT, c = i % F_OUT;
    W2t[c * F_HID + k] = f2bf(W2[i]);
  }
  grid.sync();

  // P1: gemm1 tiles overlapped with edge-bucket histogram
  for (int u = bid; u < NT1 + NBLK_E; u += nblk) {
    if (u < NT1)
      gemm_tile<F_HID, F_IN, true>(u, x, W1t, h1b, a1s, a1d, as1, ad1, smem, tid);
    else
      ehist_unit(u - NT1, edst, hist_blk, smem, tid);
  }
  grid.sync();

  // P2: per-bucket scan of chunk counts
  for (int u = bid; u < NB; u += nblk) escan_unit(u, hist_blk, btotal, smem, tid);
  grid.sync();

  // P3: scatter edges to bucket regions (LDS cursors, no global atomics)
  for (int u = bid; u < NBLK_E; u += nblk)
    escatter_unit(u, esrc, edst, hist_blk, staged, smem, tid);
  grid.sync();

  // P4: per-bucket CSR finalize (+self loops)
  for (int u = bid; u < NB; u += nblk)
    fine_unit(u, staged, btotal, counts, offs, csr, smem, tid);
  grid.sync();

  // P5: layer-1 aggregation (softmax + gather), ReLU, bf16 out
  for (int u = bid; u < NAGG; u += nblk)
    agg_node<F_HID, true, true>(u * 4 + wave, lane, h1b, as1, ad1, offs, counts,
                                csr, b1, hrb);
  grid.sync();

  // P6: layer-2 GEMM
  for (int u = bid; u < NT1; u += nblk)
    gemm_tile<F_OUT, F_HID, false>(u, hrb, W2t, h2b, a2s, a2d, as2, ad2, smem, tid);
  grid.sync();

  // P7: layer-2 aggregation, f32 out
  for (int u = bid; u < NAGG; u += nblk)
    agg_node<F_OUT, false, false>(u * 4 + wave, lane, h2b, as2, ad2, offs, counts,
                                  csr, b2, out);
}

// ---------------------------------------------------------------- launch ----
extern "C" void kernel_launch(void* const* d_in, const int* in_sizes, int n_in,
                              void* d_out, int out_size, void* d_ws, size_t ws_size,
                              hipStream_t stream) {
  const float* x = (const float*)d_in[0];
  const int* ei = (const int*)d_in[1];
  const float* W1 = (const float*)d_in[2];
  const float* a1s = (const float*)d_in[3];
  const float* a1d = (const float*)d_in[4];
  const float* b1 = (const float*)d_in[5];
  const float* W2 = (const float*)d_in[6];
  const float* a2s = (const float*)d_in[7];
  const float* a2d = (const float*)d_in[8];
  const float* b2 = (const float*)d_in[9];
  float* out = (float*)d_out;
  char* ws = (char*)d_ws;

  // co-residency-safe grid size (pure host query; capture-legal)
  int maxb = 0;
  if (hipOccupancyMaxActiveBlocksPerMultiprocessor(
          &maxb, (const void*)mega_kernel, 256, 0) != hipSuccess || maxb <= 0)
    maxb = 4;
  if (maxb > 4) maxb = 4;
  dim3 grid(maxb * 256), block(256);

  void* args[] = {(void*)&x,   (void*)&ei,  (void*)&W1,  (void*)&a1s,
                  (void*)&a1d, (void*)&b1,  (void*)&W2,  (void*)&a2s,
                  (void*)&a2d, (void*)&b2,  (void*)&out, (void*)&ws};
  hipLaunchCooperativeKernel((const void*)mega_kernel, grid, block, args, 0, stream);
}